// Round 12
// baseline (270.302 us; speedup 1.0000x reference)
//
#include <hip/hip_runtime.h>
#include <stdint.h>

typedef unsigned short u16;
typedef __attribute__((ext_vector_type(8))) short short8;
typedef __attribute__((ext_vector_type(4))) float f32x4;
typedef __attribute__((ext_vector_type(4))) unsigned short u16x4;
typedef __attribute__((ext_vector_type(2))) unsigned int uint2v;

#define MFMA16(a,b,c) __builtin_amdgcn_mfma_f32_16x16x32_bf16((a),(b),(c),0,0,0)
#define VWAIT(n) asm volatile("s_waitcnt vmcnt(" #n ")" ::: "memory")

__device__ __forceinline__ void gload16(const void* g, void* l) {
  __builtin_amdgcn_global_load_lds(
      (__attribute__((address_space(1))) void*)(uintptr_t)(g),
      (__attribute__((address_space(3))) void*)(uint32_t)(uintptr_t)(l),
      16, 0, 0);
}

__device__ __forceinline__ u16 f2bf(float x) {
  union { float f; unsigned u; } v; v.f = x;
  unsigned r = v.u + 0x7fffu + ((v.u >> 16) & 1u);
  return (u16)(r >> 16);
}
__device__ __forceinline__ unsigned pack2(float a, float b) {
  return (unsigned)f2bf(a) | ((unsigned)f2bf(b) << 16);
}

// ---------------- fused prep: cast inputs (z<3) + transpose weights (z>=3) ----------------
__global__ __launch_bounds__(256) void prep_kernel(const float* x0, const float* x1, const float* x2,
                                                   u16* y0, u16* y1, u16* y2,
                                                   const float* w0, const float* w1, const float* w2, const float* w3,
                                                   u16* t0, u16* t1, u16* t2, u16* t3) {
  __shared__ float tile[32][33];
  int z = blockIdx.y;
  if (z < 3) {
    const float* x = (z == 0) ? x0 : ((z == 1) ? x1 : x2);
    u16*         y = (z == 0) ? y0 : ((z == 1) ? y1 : y2);
    size_t i = ((size_t)blockIdx.x * 256 + threadIdx.x) * 4;
    float4 v = *(const float4*)(x + i);
    u16x4 o; o[0] = f2bf(v.x); o[1] = f2bf(v.y); o[2] = f2bf(v.z); o[3] = f2bf(v.w);
    *(u16x4*)(y + i) = o;
  } else {
    if (blockIdx.x >= 1024) return;
    const float* W; u16* T;
    switch (z - 3) {
      case 0:  W = w0; T = t0; break;
      case 1:  W = w1; T = t1; break;
      case 2:  W = w2; T = t2; break;
      default: W = w3; T = t3; break;
    }
    int k0 = (blockIdx.x >> 5) * 32, n0 = (blockIdx.x & 31) * 32;
    int tx = threadIdx.x & 31, ty = threadIdx.x >> 5;
#pragma unroll
    for (int j = 0; j < 4; ++j)
      tile[ty + 8*j][tx] = W[(size_t)(k0 + ty + 8*j) * 1024 + n0 + tx];
    __syncthreads();
#pragma unroll
    for (int j = 0; j < 4; ++j)
      T[(size_t)(n0 + ty + 8*j) * 1024 + k0 + tx] = f2bf(tile[tx][ty + 8*j]);
  }
}

// ---------------- shared GEMM core: C[128x128] = A * WT^T, 3-deep pipelined ----------------
// ZF=1: 78 nt zero-stores (bh 3..31 mask region). ZF=2: 24 nt zero-stores (bh 0..2).
// Counted waits drain only the staging loads; zero-stores ride >=2 iterations.
__device__ __forceinline__ void gemm_stage(const u16* A, const u16* BT, int row0, int col0,
                                           int tid, int w, int kt, char* la, char* lb) {
#pragma unroll
  for (int j = 0; j < 2; ++j) {
    int c = j * 256 + tid;
    int mr = c & 127, kc = c >> 7;
    gload16(A  + (size_t)(row0 + mr) * 1024 + kt*32 + kc*8, la + (j*4 + w) * 1024);
    gload16(BT + (size_t)(col0 + mr) * 1024 + kt*32 + kc*8, lb + (j*4 + w) * 1024);
  }
}

template <int ZF>
__device__ __forceinline__ void gemm_core(const u16* A, const u16* BT, int row0, int col0,
                                          char* ldsA, char* ldsB, f32x4 (&acc)[4][4],
                                          int zbase, float* zdst) {
  int tid = threadIdx.x, w = tid >> 6, lane = tid & 63;
  int u = lane >> 4, c16 = lane & 15, wr = w >> 1, wc = w & 1;
  gemm_stage(A, BT, row0, col0, tid, w, 0, ldsA, ldsB);
  gemm_stage(A, BT, row0, col0, tid, w, 1, ldsA + 8192, ldsB + 8192);
  int cur = 0;
  for (int kt = 0; kt < 32; ++kt) {
    if (ZF == 1) {
      if (kt == 0)       VWAIT(4);
      else if (kt == 1)  VWAIT(7);
      else if (kt <= 26) VWAIT(10);
      else if (kt == 27) VWAIT(7);
      else if (kt < 31)  VWAIT(4);
      else               VWAIT(0);
    } else if (ZF == 2) {
      if (kt == 0)       VWAIT(4);
      else if (kt == 1)  VWAIT(5);
      else if (kt <= 24) VWAIT(6);
      else if (kt == 25) VWAIT(5);
      else if (kt < 31)  VWAIT(4);
      else               VWAIT(0);
    } else {
      if (kt < 31) VWAIT(4);
      else         VWAIT(0);
    }
    __builtin_amdgcn_s_barrier();
    asm volatile("" ::: "memory");
    if (kt < 30) {
      int nb = cur + 2; if (nb >= 3) nb -= 3;
      gemm_stage(A, BT, row0, col0, tid, w, kt + 2, ldsA + nb*8192, ldsB + nb*8192);
    }
    __builtin_amdgcn_sched_barrier(0);   // loads strictly before stores (vmcnt order)
    if (ZF == 1 && kt < 26) {
      f32x4 z4 = {};
#pragma unroll
      for (int s = 0; s < 3; ++s) {
        int si = kt * 3 + s;              // 0..77
        int pp = zbase + (si >> 1);
        if (pp > 29695) pp = 29695;       // clamp -> duplicate zero
        int half = si & 1;
        int bh = 3 + (pp >> 10);
        int rp = pp & 1023;
        int qt1 = rp >> 6;
        int len1 = 496 - (qt1 << 4);
        int slot = (half << 8) + tid;
        if (slot > 495) slot = 495;
        int row, col4;
        if (slot < len1) { row = rp;        col4 = (qt1 << 4) + 16 + slot; }
        else             { row = 2047 - rp; col4 = slot + 16; }
        __builtin_nontemporal_store(z4,
            (f32x4*)(zdst + ((size_t)bh * 2048 + row) * 2048 + (size_t)col4 * 4));
      }
      __builtin_amdgcn_sched_barrier(0);
    }
    if (ZF == 2 && kt < 24) {
      f32x4 z4 = {};
      int pp = zbase + (kt >> 1);         // 0..3071 (bh 0..2)
      int half = kt & 1;
      int bh = pp >> 10;
      int rp = pp & 1023;
      int qt1 = rp >> 6;
      int len1 = 496 - (qt1 << 4);
      int slot = (half << 8) + tid;
      if (slot > 495) slot = 495;
      int row, col4;
      if (slot < len1) { row = rp;        col4 = (qt1 << 4) + 16 + slot; }
      else             { row = 2047 - rp; col4 = slot + 16; }
      __builtin_nontemporal_store(z4,
          (f32x4*)(zdst + ((size_t)bh * 2048 + row) * 2048 + (size_t)col4 * 4));
      __builtin_amdgcn_sched_barrier(0);
    }
    const char* la = ldsA + cur * 8192;
    const char* lb = ldsB + cur * 8192;
    short8 af[4], bv[4];
#pragma unroll
    for (int i = 0; i < 4; ++i) {
      af[i] = *(const short8*)(la + (u*128 + wr*64 + i*16 + c16) * 16);
      bv[i] = *(const short8*)(lb + (u*128 + wc*64 + i*16 + c16) * 16);
    }
#pragma unroll
    for (int i = 0; i < 4; ++i)
#pragma unroll
      for (int n = 0; n < 4; ++n)
        acc[i][n] = MFMA16(af[i], bv[n], acc[i][n]);
    cur = cur + 1; if (cur >= 3) cur = 0;
  }
}

// ---------------- QKV projections (XCD row-clustered, + zero-fill bh 3..31) ----------------
__global__ __launch_bounds__(256) void gemm_qkv(const u16* Xq, const u16* Xk, const u16* Xv,
                                                const u16* WTq, const u16* WTk, const u16* WTv,
                                                u16* Qh, u16* Kh, u16* VhT, float* attnO) {
  __shared__ char ldsA[24576], ldsB[24576];
  int z = blockIdx.z;
  const u16* A  = (z == 0) ? Xq  : ((z == 1) ? Xk  : Xv);
  const u16* BT = (z == 0) ? WTq : ((z == 1) ? WTk : WTv);
  int id = blockIdx.x + 32 * blockIdx.y;
  int xcd = id & 7, rank = id >> 3;
  int row0 = (xcd * 4 + (rank & 3)) * 128;
  int col0 = (rank >> 2) * 128;
  int id768 = blockIdx.x + 32 * blockIdx.y + 256 * z;
  int zbase = id768 * 39;
  f32x4 acc[4][4] = {};
  gemm_core<1>(A, BT, row0, col0, ldsA, ldsB, acc, zbase, attnO);
  int tid = threadIdx.x, w = tid >> 6, lane = tid & 63, u = lane >> 4, c16 = lane & 15;
  int wr = w >> 1, wc = w & 1;
  if (z == 2) {
#pragma unroll
    for (int i = 0; i < 4; ++i)
#pragma unroll
      for (int n = 0; n < 4; ++n) {
        int rowb = row0 + wr*64 + i*16 + u*4;
        int colg = col0 + wc*64 + n*16 + c16;
        int b = rowb >> 11, s = rowb & 2047;
        int h = colg >> 6, d = colg & 63;
        u16x4 pv;
#pragma unroll
        for (int r = 0; r < 4; ++r) pv[r] = f2bf(acc[i][n][r]);
        *(u16x4*)(VhT + ((size_t)(b*16 + h) * 64 + d) * 2048 + s) = pv;
      }
  } else {
#pragma unroll
    for (int i = 0; i < 4; ++i)
#pragma unroll
      for (int n = 0; n < 4; ++n)
#pragma unroll
        for (int r = 0; r < 4; ++r) {
          int row = row0 + wr*64 + i*16 + u*4 + r;
          int colg = col0 + wc*64 + n*16 + c16;
          int b = row >> 11, s = row & 2047;
          int h = colg >> 6, d = colg & 63;
          float v = acc[i][n][r];
          // Q pre-scaled by (1/8)*log2(e): QK^T lands in log2 domain -> bare v_exp_f32
          if (z == 0) Qh[((size_t)(b*16 + h) * 2048 + s) * 64 + d] = f2bf(v * 0.18033688f);
          else        Kh[((size_t)(b*16 + h) * 2048 + s) * 64 + d] = f2bf(v);
        }
  }
}

// ---------------- output projection + residual (XCD row-clustered, + zero-fill bh 0..2) ----------------
__global__ __launch_bounds__(256) void gemm_out(const u16* Ctx, const u16* WTo,
                                                const float* resid, float* outF, float* attnO) {
  __shared__ char ldsA[24576], ldsB[24576];
  int id = blockIdx.x + 32 * blockIdx.y;
  int xcd = id & 7, rank = id >> 3;
  int row0 = (xcd * 4 + (rank & 3)) * 128;
  int col0 = (rank >> 2) * 128;
  int zbase = id * 12;                 // 256 blocks x 12 pairs = 3072 = 3 bh x 1024
  f32x4 acc[4][4] = {};
  gemm_core<2>(Ctx, WTo, row0, col0, ldsA, ldsB, acc, zbase, attnO);
  int tid = threadIdx.x, w = tid >> 6, lane = tid & 63, u = lane >> 4, c16 = lane & 15;
  int wr = w >> 1, wc = w & 1;
#pragma unroll
  for (int i = 0; i < 4; ++i)
#pragma unroll
    for (int n = 0; n < 4; ++n)
#pragma unroll
      for (int r = 0; r < 4; ++r) {
        int row = row0 + wr*64 + i*16 + u*4 + r;
        int colg = col0 + wc*64 + n*16 + c16;
        size_t idx = (size_t)row * 1024 + colg;
        outF[idx] = acc[i][n][r] + resid[idx];
      }
}

// ---------------- fused causal attention (pair-balanced, counted-vmcnt, setprio) ----------------
__device__ __forceinline__ void qk_tile(const char* Kbuf, short8 qf0, short8 qf1,
                                        int cq, int u, int rho, f32x4 (&acc)[4]) {
#pragma unroll
  for (int st = 0; st < 4; ++st) {
    short8 a0 = *(const short8*)(Kbuf + (st*16 + cq) * 128 + ((u*16) ^ rho));
    short8 a1 = *(const short8*)(Kbuf + (st*16 + cq) * 128 + ((64 + u*16) ^ rho));
    acc[st] = MFMA16(a0, qf0, acc[st]);
    acc[st] = MFMA16(a1, qf1, acc[st]);
  }
}

__device__ __forceinline__ void stage_k64(const u16* pan, int kt, char* buf, int tid, int w) {
#pragma unroll
  for (int j = 0; j < 2; ++j) {
    int c = j * 256 + tid;
    int row = c >> 3;
    int cc = (c & 7) ^ (row & 7);
    gload16(pan + (size_t)(kt*64 + row) * 64 + cc*8, buf + (j*4 + w) * 1024);
  }
}
__device__ __forceinline__ void stage_v64(const u16* vpan, int kt, char* buf, int tid, int w) {
#pragma unroll
  for (int j = 0; j < 2; ++j) {
    int c = j * 256 + tid;
    int d = c >> 3;
    int cc = (c & 7) ^ (d & 7);
    gload16(vpan + (size_t)d * 2048 + kt*64 + cc*8, buf + (j*4 + w) * 1024);
  }
}

// pass-1 tile: accumulate sum of exp2(S') for one q-tile (S' already log2-scaled)
__device__ __forceinline__ void tile_pass1(const char* Kcur, short8 qf0, short8 qf1,
                                           int q, int q0t, int kt, int ktd_t,
                                           int cq, int u, int rho, float& ls) {
  f32x4 acc[4] = {};
  qk_tile(Kcur, qf0, qf1, cq, u, rho, acc);
  if (kt == ktd_t) {
#pragma unroll
    for (int st = 0; st < 4; ++st)
#pragma unroll
      for (int r = 0; r < 4; ++r) {
        int key = q0t + st*16 + u*4 + r;
        if (key > q) acc[st][r] = -1e30f;
      }
  }
#pragma unroll
  for (int st = 0; st < 4; ++st)
#pragma unroll
    for (int r = 0; r < 4; ++r) ls += __builtin_amdgcn_exp2f(acc[st][r]);
}

// pass-2 tile: probs direct nt-store from registers (own-row, 4 contiguous f32);
// PV A-fragments via bf16 packed per-wave LDS buffer (R1 layout, ~2-way banks)
__device__ __forceinline__ void tile_pass2(const char* Kcur, const char* Vcur, char* Pw,
                                           short8 qf0, short8 qf1, int q, int q0t, int kt, int ktd_t,
                                           float rl, float* apan, int w, int u, int cq,
                                           int rho, f32x4 (&ctx)[4]) {
  f32x4 acc[4] = {};
  __builtin_amdgcn_s_setprio(1);
  qk_tile(Kcur, qf0, qf1, cq, u, rho, acc);
  if (kt == ktd_t) {
#pragma unroll
    for (int st = 0; st < 4; ++st)
#pragma unroll
      for (int r = 0; r < 4; ++r) {
        int key = q0t + st*16 + u*4 + r;
        if (key > q) acc[st][r] = -1e30f;
      }
  }
  float* arow = apan + (size_t)q * 2048;
#pragma unroll
  for (int st = 0; st < 4; ++st) {
    f32x4 p;
#pragma unroll
    for (int r = 0; r < 4; ++r) p[r] = __builtin_amdgcn_exp2f(acc[st][r]) * rl;
    __builtin_nontemporal_store(p, (f32x4*)(arow + kt*64 + st*16 + u*4));
    uint2v pk;
    pk[0] = pack2(p[0], p[1]);
    pk[1] = pack2(p[2], p[3]);
    *(uint2v*)(Pw + ((cq*128 + st*32 + u*8) ^ rho)) = pk;
  }
  __builtin_amdgcn_sched_barrier(0);
#pragma unroll
  for (int wd = 0; wd < 2; ++wd) {
    short8 pa = *(const short8*)(Pw + ((cq*128 + wd*64 + u*16) ^ rho));
#pragma unroll
    for (int nt = 0; nt < 4; ++nt) {
      short8 vb = *(const short8*)(Vcur + (nt*16 + cq) * 128 + ((wd*64 + u*16) ^ rho));
      ctx[nt] = MFMA16(pa, vb, ctx[nt]);
    }
  }
  __builtin_amdgcn_s_setprio(0);
  __builtin_amdgcn_sched_barrier(0);
}

__global__ __launch_bounds__(256) void attn_fused(const u16* Qh, const u16* Kh, const u16* VhT,
                                                  float* attnO, u16* Ctx) {
  __shared__ char Kl[3][8192];
  __shared__ char Vl[2][8192];
  __shared__ char Pl[4][2048];      // per-wave bf16 P tiles (16 q-rows x 64 keys)
  int tid = threadIdx.x, w = tid >> 6, lane = tid & 63;
  int u = lane >> 4, cq = lane & 15;
  // XCD clustering: each bh's 16 pair-blocks on one XCD (id%8 ~ XCD heuristic)
  int id = blockIdx.x;
  int xcd = id & 7, rank = id >> 3;
  int bh = xcd * 4 + (rank >> 4);
  int pi = rank & 15;
  int tlo = pi, thi = 31 - pi;
  int q0lo = tlo * 64, q0hi = thi * 64;
  int qlo = q0lo + w*16 + cq;
  int qhi = q0hi + w*16 + cq;
  int rho = (cq & 7) << 4;
  const u16* Kpan = Kh  + (size_t)bh * (2048 * 64);
  const u16* Vpan = VhT + (size_t)bh * (64 * 2048);
  const u16* Qlo = Qh + ((size_t)bh * 2048 + qlo) * 64;
  const u16* Qhi = Qh + ((size_t)bh * 2048 + qhi) * 64;
  short8 qlo0 = *(const short8*)(Qlo + u*8);
  short8 qlo1 = *(const short8*)(Qlo + 32 + u*8);
  short8 qhi0 = *(const short8*)(Qhi + u*8);
  short8 qhi1 = *(const short8*)(Qhi + 32 + u*8);

  // ---- pass 1: row sums of exp2(S'), 3-deep K prefetch ----
  float ls_lo = 0.f, ls_hi = 0.f;
  stage_k64(Kpan, 0, Kl[0], tid, w);
  stage_k64(Kpan, 1, Kl[1], tid, w);
  int cur1 = 0;
  for (int kt = 0; kt <= thi; ++kt) {
    if (kt < thi) VWAIT(4);
    else          VWAIT(0);
    __builtin_amdgcn_s_barrier();
    asm volatile("" ::: "memory");
    if (kt + 2 <= thi) {
      int nb = cur1 + 2; if (nb >= 3) nb -= 3;
      stage_k64(Kpan, kt + 2, Kl[nb], tid, w);
    }
    __builtin_amdgcn_sched_barrier(0);
    __builtin_amdgcn_s_setprio(1);
    tile_pass1(Kl[cur1], qhi0, qhi1, qhi, q0hi, kt, thi, cq, u, rho, ls_hi);
    if (kt <= tlo)
      tile_pass1(Kl[cur1], qlo0, qlo1, qlo, q0lo, kt, tlo, cq, u, rho, ls_lo);
    __builtin_amdgcn_s_setprio(0);
    cur1 = cur1 + 1; if (cur1 >= 3) cur1 = 0;
  }
  ls_lo += __shfl_xor(ls_lo, 16);  ls_lo += __shfl_xor(ls_lo, 32);
  ls_hi += __shfl_xor(ls_hi, 16);  ls_hi += __shfl_xor(ls_hi, 32);
  float rl_lo = 1.f / ls_lo, rl_hi = 1.f / ls_hi;

  // handoff: all waves done reading Kl before pass-2 staging overwrites it
  asm volatile("" ::: "memory");
  __builtin_amdgcn_s_barrier();
  asm volatile("" ::: "memory");

  // ---- pass 2: probs + ctx, shared K/V staging; stores ride across barriers ----
  f32x4 ctx_lo[4] = {}, ctx_hi[4] = {};
  float* apan = attnO + (size_t)bh * 2048 * 2048;
  char* Pw = Pl[w];
  stage_k64(Kpan, 0, Kl[0], tid, w);
  stage_v64(Vpan, 0, Vl[0], tid, w);
  VWAIT(0);
  __builtin_amdgcn_s_barrier();
  asm volatile("" ::: "memory");
  for (int kt = 0; kt <= thi; ++kt) {
    int cur = kt & 1;
    if (kt < thi) {
      stage_k64(Kpan, kt + 1, Kl[cur ^ 1], tid, w);
      stage_v64(Vpan, kt + 1, Vl[cur ^ 1], tid, w);
    }
    __builtin_amdgcn_sched_barrier(0);
    tile_pass2(Kl[cur], Vl[cur], Pw, qhi0, qhi1, qhi, q0hi, kt, thi,
               rl_hi, apan, w, u, cq, rho, ctx_hi);
    bool lo_act = (kt <= tlo);
    if (lo_act)
      tile_pass2(Kl[cur], Vl[cur], Pw, qlo0, qlo1, qlo, q0lo, kt, tlo,
                 rl_lo, apan, w, u, cq, rho, ctx_lo);
    if (kt < thi) {
      // loads were issued first: counted wait drains the 4 prefetch load-ops,
      // leaves this iteration's prob stores in flight across the barrier
      if (lo_act) VWAIT(8);
      else        VWAIT(4);
      __builtin_amdgcn_s_barrier();
      asm volatile("" ::: "memory");
    }
  }

  // masked-tile zeros: bh 3..31 by gemm_qkv ZF=1, bh 0..2 by gemm_out ZF=2 (runs after)

  // ctx writes: [BS][1024] bf16 for the output GEMM
  int b = bh >> 4, h = bh & 15;
#pragma unroll
  for (int nt = 0; nt < 4; ++nt)
#pragma unroll
    for (int r = 0; r < 4; ++r) {
      int qr = q0lo + w*16 + u*4 + r;
      Ctx[((size_t)b * 2048 + qr) * 1024 + h*64 + nt*16 + cq] = f2bf(ctx_lo[nt][r]);
    }
#pragma unroll
  for (int nt = 0; nt < 4; ++nt)
#pragma unroll
    for (int r = 0; r < 4; ++r) {
      int qr = q0hi + w*16 + u*4 + r;
      Ctx[((size_t)b * 2048 + qr) * 1024 + h*64 + nt*16 + cq] = f2bf(ctx_hi[nt][r]);
    }
}

// ---------------- LayerNorm over 1024 cols ----------------
__global__ __launch_bounds__(256) void ln_kernel(const float* X, const float* g, const float* b, float* out) {
  int row = blockIdx.x, tid = threadIdx.x;
  float4 v = *(const float4*)(X + (size_t)row * 1024 + tid * 4);
  float s  = v.x + v.y + v.z + v.w;
  float q2 = v.x*v.x + v.y*v.y + v.z*v.z + v.w*v.w;
#pragma unroll
  for (int off = 32; off; off >>= 1) { s += __shfl_xor(s, off); q2 += __shfl_xor(q2, off); }
  __shared__ float red[8];
  int w = tid >> 6, lane = tid & 63;
  if (lane == 0) { red[w] = s; red[4 + w] = q2; }
  __syncthreads();
  s  = red[0] + red[1] + red[2] + red[3];
  q2 = red[4] + red[5] + red[6] + red[7];
  float mean = s * (1.f / 1024.f);
  float var  = q2 * (1.f / 1024.f) - mean * mean;
  float rs   = rsqrtf(var + 1e-5f);
  float4 gv = *(const float4*)(g + tid * 4);
  float4 bv = *(const float4*)(b + tid * 4);
  float4 o;
  o.x = (v.x - mean) * rs * gv.x + bv.x;
  o.y = (v.y - mean) * rs * gv.y + bv.y;
  o.z = (v.z - mean) * rs * gv.z + bv.z;
  o.w = (v.w - mean) * rs * gv.w + bv.w;
  *(float4*)(out + (size_t)row * 1024 + tid * 4) = o;
}

extern "C" void kernel_launch(void* const* d_in, const int* in_sizes, int n_in,
                              void* d_out, int out_size, void* d_ws, size_t ws_size,
                              hipStream_t stream) {
  (void)in_sizes; (void)n_in; (void)out_size; (void)ws_size;
  const float* inQ = (const float*)d_in[0];
  const float* inK = (const float*)d_in[1];
  const float* inV = (const float*)d_in[2];
  const float* Wq  = (const float*)d_in[4];
  const float* Wk  = (const float*)d_in[5];
  const float* Wv  = (const float*)d_in[6];
  const float* Wo  = (const float*)d_in[7];
  const float* gam = (const float*)d_in[8];
  const float* bet = (const float*)d_in[9];
  float* out   = (float*)d_out;
  float* attnO = out + (size_t)4194304;

  char* ws = (char*)d_ws;
  u16*   WTo    = (u16*)ws;
  u16*   Qh     = (u16*)(ws + 2097152);
  u16*   Kh     = (u16*)(ws + 2097152 + (size_t)8388608);
  u16*   VhT    = (u16*)(ws + 2097152 + (size_t)2*8388608);
  u16*   Ctx    = (u16*)(ws + 2097152 + (size_t)3*8388608);
  float* OutLin = (float*)(ws + 2097152 + (size_t)4*8388608);

  // prep scratch lives in attnO[0 .. 30MB): bh0 + most of bh1; fully overwritten
  // by attn probs (lower) + gemm_out ZF=2 zeros (upper) afterwards
  u16* Xbq = (u16*)attnO;
  u16* Xbk = Xbq + (size_t)4194304;
  u16* Xbv = Xbk + (size_t)4194304;
  u16* WTq = Xbv + (size_t)4194304;
  u16* WTk = WTq + (size_t)1048576;
  u16* WTv = WTk + (size_t)1048576;

  prep_kernel<<<dim3(4096, 7), 256, 0, stream>>>(inQ, inK, inV, Xbq, Xbk, Xbv,
                                                 Wq, Wk, Wv, Wo, WTq, WTk, WTv, WTo);
  gemm_qkv<<<dim3(32, 8, 3), 256, 0, stream>>>(Xbq, Xbk, Xbv, WTq, WTk, WTv, Qh, Kh, VhT, attnO);
  attn_fused<<<512, 256, 0, stream>>>(Qh, Kh, VhT, attnO, Ctx);
  gemm_out<<<dim3(32, 8), 256, 0, stream>>>(Ctx, WTo, inQ, OutLin, attnO);
  ln_kernel<<<4096, 256, 0, stream>>>(OutLin, gam, bet, out);
}

// Round 13
// 230.350 us; speedup vs baseline: 1.1734x; 1.1734x over previous
//
#include <hip/hip_runtime.h>
#include <stdint.h>

typedef unsigned short u16;
typedef __attribute__((ext_vector_type(8))) short short8;
typedef __attribute__((ext_vector_type(4))) float f32x4;
typedef __attribute__((ext_vector_type(4))) unsigned short u16x4;
typedef __attribute__((ext_vector_type(4))) unsigned int uint4v;

#define MFMA16(a,b,c) __builtin_amdgcn_mfma_f32_16x16x32_bf16((a),(b),(c),0,0,0)
#define VWAIT(n) asm volatile("s_waitcnt vmcnt(" #n ")" ::: "memory")

__device__ __forceinline__ void gload16(const void* g, void* l) {
  __builtin_amdgcn_global_load_lds(
      (__attribute__((address_space(1))) void*)(uintptr_t)(g),
      (__attribute__((address_space(3))) void*)(uint32_t)(uintptr_t)(l),
      16, 0, 0);
}

__device__ __forceinline__ u16 f2bf(float x) {
  union { float f; unsigned u; } v; v.f = x;
  unsigned r = v.u + 0x7fffu + ((v.u >> 16) & 1u);
  return (u16)(r >> 16);
}
__device__ __forceinline__ unsigned pack2(float a, float b) {
  return (unsigned)f2bf(a) | ((unsigned)f2bf(b) << 16);
}

// ---------------- fused prep: cast inputs (z<3) + transpose weights (z>=3) ----------------
__global__ __launch_bounds__(256) void prep_kernel(const float* x0, const float* x1, const float* x2,
                                                   u16* y0, u16* y1, u16* y2,
                                                   const float* w0, const float* w1, const float* w2, const float* w3,
                                                   u16* t0, u16* t1, u16* t2, u16* t3) {
  __shared__ float tile[32][33];
  int z = blockIdx.y;
  if (z < 3) {
    const float* x = (z == 0) ? x0 : ((z == 1) ? x1 : x2);
    u16*         y = (z == 0) ? y0 : ((z == 1) ? y1 : y2);
    size_t i = ((size_t)blockIdx.x * 256 + threadIdx.x) * 4;
    float4 v = *(const float4*)(x + i);
    u16x4 o; o[0] = f2bf(v.x); o[1] = f2bf(v.y); o[2] = f2bf(v.z); o[3] = f2bf(v.w);
    *(u16x4*)(y + i) = o;
  } else {
    if (blockIdx.x >= 1024) return;
    const float* W; u16* T;
    switch (z - 3) {
      case 0:  W = w0; T = t0; break;
      case 1:  W = w1; T = t1; break;
      case 2:  W = w2; T = t2; break;
      default: W = w3; T = t3; break;
    }
    int k0 = (blockIdx.x >> 5) * 32, n0 = (blockIdx.x & 31) * 32;
    int tx = threadIdx.x & 31, ty = threadIdx.x >> 5;
#pragma unroll
    for (int j = 0; j < 4; ++j)
      tile[ty + 8*j][tx] = W[(size_t)(k0 + ty + 8*j) * 1024 + n0 + tx];
    __syncthreads();
#pragma unroll
    for (int j = 0; j < 4; ++j)
      T[(size_t)(n0 + ty + 8*j) * 1024 + k0 + tx] = f2bf(tile[tx][ty + 8*j]);
  }
}

// ---------------- shared GEMM core: C[128x128] = A * WT^T, 3-deep pipelined ----------------
// ZF=1: 78 nt zero-stores (bh 3..31 mask region). ZF=2: 24 nt zero-stores (bh 0..2).
// Counted waits drain only the staging loads; zero-stores ride >=2 iterations.
__device__ __forceinline__ void gemm_stage(const u16* A, const u16* BT, int row0, int col0,
                                           int tid, int w, int kt, char* la, char* lb) {
#pragma unroll
  for (int j = 0; j < 2; ++j) {
    int c = j * 256 + tid;
    int mr = c & 127, kc = c >> 7;
    gload16(A  + (size_t)(row0 + mr) * 1024 + kt*32 + kc*8, la + (j*4 + w) * 1024);
    gload16(BT + (size_t)(col0 + mr) * 1024 + kt*32 + kc*8, lb + (j*4 + w) * 1024);
  }
}

template <int ZF>
__device__ __forceinline__ void gemm_core(const u16* A, const u16* BT, int row0, int col0,
                                          char* ldsA, char* ldsB, f32x4 (&acc)[4][4],
                                          int zbase, float* zdst) {
  int tid = threadIdx.x, w = tid >> 6, lane = tid & 63;
  int u = lane >> 4, c16 = lane & 15, wr = w >> 1, wc = w & 1;
  gemm_stage(A, BT, row0, col0, tid, w, 0, ldsA, ldsB);
  gemm_stage(A, BT, row0, col0, tid, w, 1, ldsA + 8192, ldsB + 8192);
  int cur = 0;
  for (int kt = 0; kt < 32; ++kt) {
    if (ZF == 1) {
      if (kt == 0)       VWAIT(4);
      else if (kt == 1)  VWAIT(7);
      else if (kt <= 26) VWAIT(10);
      else if (kt == 27) VWAIT(7);
      else if (kt < 31)  VWAIT(4);
      else               VWAIT(0);
    } else if (ZF == 2) {
      if (kt == 0)       VWAIT(4);
      else if (kt == 1)  VWAIT(5);
      else if (kt <= 24) VWAIT(6);
      else if (kt == 25) VWAIT(5);
      else if (kt < 31)  VWAIT(4);
      else               VWAIT(0);
    } else {
      if (kt < 31) VWAIT(4);
      else         VWAIT(0);
    }
    __builtin_amdgcn_s_barrier();
    asm volatile("" ::: "memory");
    if (kt < 30) {
      int nb = cur + 2; if (nb >= 3) nb -= 3;
      gemm_stage(A, BT, row0, col0, tid, w, kt + 2, ldsA + nb*8192, ldsB + nb*8192);
    }
    __builtin_amdgcn_sched_barrier(0);   // loads strictly before stores (vmcnt order)
    if (ZF == 1 && kt < 26) {
      f32x4 z4 = {};
#pragma unroll
      for (int s = 0; s < 3; ++s) {
        int si = kt * 3 + s;              // 0..77
        int pp = zbase + (si >> 1);
        if (pp > 29695) pp = 29695;       // clamp -> duplicate zero
        int half = si & 1;
        int bh = 3 + (pp >> 10);
        int rp = pp & 1023;
        int qt1 = rp >> 6;
        int len1 = 496 - (qt1 << 4);
        int slot = (half << 8) + tid;
        if (slot > 495) slot = 495;
        int row, col4;
        if (slot < len1) { row = rp;        col4 = (qt1 << 4) + 16 + slot; }
        else             { row = 2047 - rp; col4 = slot + 16; }
        __builtin_nontemporal_store(z4,
            (f32x4*)(zdst + ((size_t)bh * 2048 + row) * 2048 + (size_t)col4 * 4));
      }
      __builtin_amdgcn_sched_barrier(0);
    }
    if (ZF == 2 && kt < 24) {
      f32x4 z4 = {};
      int pp = zbase + (kt >> 1);         // 0..3071 (bh 0..2)
      int half = kt & 1;
      int bh = pp >> 10;
      int rp = pp & 1023;
      int qt1 = rp >> 6;
      int len1 = 496 - (qt1 << 4);
      int slot = (half << 8) + tid;
      if (slot > 495) slot = 495;
      int row, col4;
      if (slot < len1) { row = rp;        col4 = (qt1 << 4) + 16 + slot; }
      else             { row = 2047 - rp; col4 = slot + 16; }
      __builtin_nontemporal_store(z4,
          (f32x4*)(zdst + ((size_t)bh * 2048 + row) * 2048 + (size_t)col4 * 4));
      __builtin_amdgcn_sched_barrier(0);
    }
    const char* la = ldsA + cur * 8192;
    const char* lb = ldsB + cur * 8192;
    short8 af[4], bv[4];
#pragma unroll
    for (int i = 0; i < 4; ++i) {
      af[i] = *(const short8*)(la + (u*128 + wr*64 + i*16 + c16) * 16);
      bv[i] = *(const short8*)(lb + (u*128 + wc*64 + i*16 + c16) * 16);
    }
#pragma unroll
    for (int i = 0; i < 4; ++i)
#pragma unroll
      for (int n = 0; n < 4; ++n)
        acc[i][n] = MFMA16(af[i], bv[n], acc[i][n]);
    cur = cur + 1; if (cur >= 3) cur = 0;
  }
}

// ---------------- QKV projections (XCD row-clustered, + zero-fill bh 3..31) ----------------
__global__ __launch_bounds__(256) void gemm_qkv(const u16* Xq, const u16* Xk, const u16* Xv,
                                                const u16* WTq, const u16* WTk, const u16* WTv,
                                                u16* Qh, u16* Kh, u16* VhT, float* attnO) {
  __shared__ char ldsA[24576], ldsB[24576];
  int z = blockIdx.z;
  const u16* A  = (z == 0) ? Xq  : ((z == 1) ? Xk  : Xv);
  const u16* BT = (z == 0) ? WTq : ((z == 1) ? WTk : WTv);
  int id = blockIdx.x + 32 * blockIdx.y;
  int xcd = id & 7, rank = id >> 3;
  int row0 = (xcd * 4 + (rank & 3)) * 128;
  int col0 = (rank >> 2) * 128;
  int id768 = blockIdx.x + 32 * blockIdx.y + 256 * z;
  int zbase = id768 * 39;
  f32x4 acc[4][4] = {};
  gemm_core<1>(A, BT, row0, col0, ldsA, ldsB, acc, zbase, attnO);
  int tid = threadIdx.x, w = tid >> 6, lane = tid & 63, u = lane >> 4, c16 = lane & 15;
  int wr = w >> 1, wc = w & 1;
  if (z == 2) {
#pragma unroll
    for (int i = 0; i < 4; ++i)
#pragma unroll
      for (int n = 0; n < 4; ++n) {
        int rowb = row0 + wr*64 + i*16 + u*4;
        int colg = col0 + wc*64 + n*16 + c16;
        int b = rowb >> 11, s = rowb & 2047;
        int h = colg >> 6, d = colg & 63;
        u16x4 pv;
#pragma unroll
        for (int r = 0; r < 4; ++r) pv[r] = f2bf(acc[i][n][r]);
        *(u16x4*)(VhT + ((size_t)(b*16 + h) * 64 + d) * 2048 + s) = pv;
      }
  } else {
#pragma unroll
    for (int i = 0; i < 4; ++i)
#pragma unroll
      for (int n = 0; n < 4; ++n)
#pragma unroll
        for (int r = 0; r < 4; ++r) {
          int row = row0 + wr*64 + i*16 + u*4 + r;
          int colg = col0 + wc*64 + n*16 + c16;
          int b = row >> 11, s = row & 2047;
          int h = colg >> 6, d = colg & 63;
          float v = acc[i][n][r];
          // Q pre-scaled by (1/8)*log2(e): QK^T lands in log2 domain -> bare v_exp_f32
          if (z == 0) Qh[((size_t)(b*16 + h) * 2048 + s) * 64 + d] = f2bf(v * 0.18033688f);
          else        Kh[((size_t)(b*16 + h) * 2048 + s) * 64 + d] = f2bf(v);
        }
  }
}

// ---------------- output projection + residual (XCD row-clustered, + zero-fill bh 0..2) ----------------
__global__ __launch_bounds__(256) void gemm_out(const u16* Ctx, const u16* WTo,
                                                const float* resid, float* outF, float* attnO) {
  __shared__ char ldsA[24576], ldsB[24576];
  int id = blockIdx.x + 32 * blockIdx.y;
  int xcd = id & 7, rank = id >> 3;
  int row0 = (xcd * 4 + (rank & 3)) * 128;
  int col0 = (rank >> 2) * 128;
  int zbase = id * 12;                 // 256 blocks x 12 pairs = 3072 = 3 bh x 1024
  f32x4 acc[4][4] = {};
  gemm_core<2>(Ctx, WTo, row0, col0, ldsA, ldsB, acc, zbase, attnO);
  int tid = threadIdx.x, w = tid >> 6, lane = tid & 63, u = lane >> 4, c16 = lane & 15;
  int wr = w >> 1, wc = w & 1;
#pragma unroll
  for (int i = 0; i < 4; ++i)
#pragma unroll
    for (int n = 0; n < 4; ++n)
#pragma unroll
      for (int r = 0; r < 4; ++r) {
        int row = row0 + wr*64 + i*16 + u*4 + r;
        int colg = col0 + wc*64 + n*16 + c16;
        size_t idx = (size_t)row * 1024 + colg;
        outF[idx] = acc[i][n][r] + resid[idx];
      }
}

// ---------------- fused causal attention (pair-balanced, counted-vmcnt, setprio) ----------------
__device__ __forceinline__ void qk_tile(const char* Kbuf, short8 qf0, short8 qf1,
                                        int cq, int u, int rho, f32x4 (&acc)[4]) {
#pragma unroll
  for (int st = 0; st < 4; ++st) {
    short8 a0 = *(const short8*)(Kbuf + (st*16 + cq) * 128 + ((u*16) ^ rho));
    short8 a1 = *(const short8*)(Kbuf + (st*16 + cq) * 128 + ((64 + u*16) ^ rho));
    acc[st] = MFMA16(a0, qf0, acc[st]);
    acc[st] = MFMA16(a1, qf1, acc[st]);
  }
}

__device__ __forceinline__ void stage_k64(const u16* pan, int kt, char* buf, int tid, int w) {
#pragma unroll
  for (int j = 0; j < 2; ++j) {
    int c = j * 256 + tid;
    int row = c >> 3;
    int cc = (c & 7) ^ (row & 7);
    gload16(pan + (size_t)(kt*64 + row) * 64 + cc*8, buf + (j*4 + w) * 1024);
  }
}
__device__ __forceinline__ void stage_v64(const u16* vpan, int kt, char* buf, int tid, int w) {
#pragma unroll
  for (int j = 0; j < 2; ++j) {
    int c = j * 256 + tid;
    int d = c >> 3;
    int cc = (c & 7) ^ (d & 7);
    gload16(vpan + (size_t)d * 2048 + kt*64 + cc*8, buf + (j*4 + w) * 1024);
  }
}

// pass-1 tile: accumulate sum of exp2(S') for one q-tile (S' already log2-scaled)
__device__ __forceinline__ void tile_pass1(const char* Kcur, short8 qf0, short8 qf1,
                                           int q, int q0t, int kt, int ktd_t,
                                           int cq, int u, int rho, float& ls) {
  f32x4 acc[4] = {};
  qk_tile(Kcur, qf0, qf1, cq, u, rho, acc);
  if (kt == ktd_t) {
#pragma unroll
    for (int st = 0; st < 4; ++st)
#pragma unroll
      for (int r = 0; r < 4; ++r) {
        int key = q0t + st*16 + u*4 + r;
        if (key > q) acc[st][r] = -1e30f;
      }
  }
#pragma unroll
  for (int st = 0; st < 4; ++st)
#pragma unroll
    for (int r = 0; r < 4; ++r) ls += __builtin_amdgcn_exp2f(acc[st][r]);
}

// pass-2 tile: probs -> f32 LDS transpose -> coalesced nt store; ctx += P*V
__device__ __forceinline__ void tile_pass2(const char* Kcur, const char* Vcur, float* Pw,
                                           short8 qf0, short8 qf1, int q, int q0t, int kt, int ktd_t,
                                           float rl, float* apan, int w, int u, int cq,
                                           int rho, int sw, f32x4 (&ctx)[4]) {
  f32x4 acc[4] = {};
  __builtin_amdgcn_s_setprio(1);
  qk_tile(Kcur, qf0, qf1, cq, u, rho, acc);
  if (kt == ktd_t) {
#pragma unroll
    for (int st = 0; st < 4; ++st)
#pragma unroll
      for (int r = 0; r < 4; ++r) {
        int key = q0t + st*16 + u*4 + r;
        if (key > q) acc[st][r] = -1e30f;
      }
  }
#pragma unroll
  for (int st = 0; st < 4; ++st) {
    f32x4 p;
#pragma unroll
    for (int r = 0; r < 4; ++r) p[r] = __builtin_amdgcn_exp2f(acc[st][r]) * rl;
    *(f32x4*)&Pw[(cq*64 + st*16 + u*4) ^ sw] = p;
  }
  __builtin_amdgcn_sched_barrier(0);
#pragma unroll
  for (int j = 0; j < 4; ++j) {
    int row = j*4 + u;
    f32x4 v = *(const f32x4*)&Pw[(row*64 + cq*4) ^ ((row & 7) << 2)];
    __builtin_nontemporal_store(v,
        (f32x4*)(apan + (size_t)(q0t + w*16 + row) * 2048 + kt*64 + cq*4));
  }
#pragma unroll
  for (int wd = 0; wd < 2; ++wd) {
    int b0 = (cq*64 + wd*32 + u*8) ^ sw;
    f32x4 pa0 = *(const f32x4*)&Pw[b0];
    f32x4 pa1 = *(const f32x4*)&Pw[b0 ^ 4];
    uint4v pk;
    pk[0] = pack2(pa0[0], pa0[1]);
    pk[1] = pack2(pa0[2], pa0[3]);
    pk[2] = pack2(pa1[0], pa1[1]);
    pk[3] = pack2(pa1[2], pa1[3]);
    union { uint4v u4; short8 s8; } cvt; cvt.u4 = pk;
    short8 pa = cvt.s8;
#pragma unroll
    for (int nt = 0; nt < 4; ++nt) {
      short8 vb = *(const short8*)(Vcur + (nt*16 + cq) * 128 + ((wd*64 + u*16) ^ rho));
      ctx[nt] = MFMA16(pa, vb, ctx[nt]);
    }
  }
  __builtin_amdgcn_s_setprio(0);
  __builtin_amdgcn_sched_barrier(0);
}

__global__ __launch_bounds__(256) void attn_fused(const u16* Qh, const u16* Kh, const u16* VhT,
                                                  float* attnO, u16* Ctx) {
  __shared__ char Kl[3][8192];
  __shared__ char Vl[2][8192];
  __shared__ float Pf[4][1024];     // per-wave 16 q-rows x 64 keys f32, XOR-swizzled words
  int tid = threadIdx.x, w = tid >> 6, lane = tid & 63;
  int u = lane >> 4, cq = lane & 15;
  // XCD clustering: each bh's 16 pair-blocks on one XCD (id%8 ~ XCD heuristic)
  int id = blockIdx.x;
  int xcd = id & 7, rank = id >> 3;
  int bh = xcd * 4 + (rank >> 4);
  int pi = rank & 15;
  int tlo = pi, thi = 31 - pi;
  int q0lo = tlo * 64, q0hi = thi * 64;
  int qlo = q0lo + w*16 + cq;
  int qhi = q0hi + w*16 + cq;
  int rho = (cq & 7) << 4;
  int sw  = (cq & 7) << 2;
  const u16* Kpan = Kh  + (size_t)bh * (2048 * 64);
  const u16* Vpan = VhT + (size_t)bh * (64 * 2048);
  const u16* Qlo = Qh + ((size_t)bh * 2048 + qlo) * 64;
  const u16* Qhi = Qh + ((size_t)bh * 2048 + qhi) * 64;
  short8 qlo0 = *(const short8*)(Qlo + u*8);
  short8 qlo1 = *(const short8*)(Qlo + 32 + u*8);
  short8 qhi0 = *(const short8*)(Qhi + u*8);
  short8 qhi1 = *(const short8*)(Qhi + 32 + u*8);

  // ---- pass 1: row sums of exp2(S'), 3-deep K prefetch ----
  float ls_lo = 0.f, ls_hi = 0.f;
  stage_k64(Kpan, 0, Kl[0], tid, w);
  stage_k64(Kpan, 1, Kl[1], tid, w);
  int cur1 = 0;
  for (int kt = 0; kt <= thi; ++kt) {
    if (kt < thi) VWAIT(4);
    else          VWAIT(0);
    __builtin_amdgcn_s_barrier();
    asm volatile("" ::: "memory");
    if (kt + 2 <= thi) {
      int nb = cur1 + 2; if (nb >= 3) nb -= 3;
      stage_k64(Kpan, kt + 2, Kl[nb], tid, w);
    }
    __builtin_amdgcn_sched_barrier(0);
    __builtin_amdgcn_s_setprio(1);
    tile_pass1(Kl[cur1], qhi0, qhi1, qhi, q0hi, kt, thi, cq, u, rho, ls_hi);
    if (kt <= tlo)
      tile_pass1(Kl[cur1], qlo0, qlo1, qlo, q0lo, kt, tlo, cq, u, rho, ls_lo);
    __builtin_amdgcn_s_setprio(0);
    cur1 = cur1 + 1; if (cur1 >= 3) cur1 = 0;
  }
  ls_lo += __shfl_xor(ls_lo, 16);  ls_lo += __shfl_xor(ls_lo, 32);
  ls_hi += __shfl_xor(ls_hi, 16);  ls_hi += __shfl_xor(ls_hi, 32);
  float rl_lo = 1.f / ls_lo, rl_hi = 1.f / ls_hi;

  // handoff: all waves done reading Kl before pass-2 staging overwrites it
  asm volatile("" ::: "memory");
  __builtin_amdgcn_s_barrier();
  asm volatile("" ::: "memory");

  // ---- pass 2: probs + ctx, shared K/V staging; stores ride across barriers ----
  f32x4 ctx_lo[4] = {}, ctx_hi[4] = {};
  float* apan = attnO + (size_t)bh * 2048 * 2048;
  float* Pw = Pf[w];
  stage_k64(Kpan, 0, Kl[0], tid, w);
  stage_v64(Vpan, 0, Vl[0], tid, w);
  VWAIT(0);
  __builtin_amdgcn_s_barrier();
  asm volatile("" ::: "memory");
  for (int kt = 0; kt <= thi; ++kt) {
    int cur = kt & 1;
    if (kt < thi) {
      stage_k64(Kpan, kt + 1, Kl[cur ^ 1], tid, w);
      stage_v64(Vpan, kt + 1, Vl[cur ^ 1], tid, w);
    }
    __builtin_amdgcn_sched_barrier(0);
    tile_pass2(Kl[cur], Vl[cur], Pw, qhi0, qhi1, qhi, q0hi, kt, thi,
               rl_hi, apan, w, u, cq, rho, sw, ctx_hi);
    bool lo_act = (kt <= tlo);
    if (lo_act)
      tile_pass2(Kl[cur], Vl[cur], Pw, qlo0, qlo1, qlo, q0lo, kt, tlo,
                 rl_lo, apan, w, u, cq, rho, sw, ctx_lo);
    if (kt < thi) {
      // loads were issued first: counted wait drains the 4 prefetch load-ops,
      // leaves this iteration's prob stores in flight across the barrier
      if (lo_act) VWAIT(8);
      else        VWAIT(4);
      __builtin_amdgcn_s_barrier();
      asm volatile("" ::: "memory");
    }
  }

  // masked-tile zeros: bh 3..31 by gemm_qkv ZF=1, bh 0..2 by gemm_out ZF=2 (runs after)

  // ctx writes: [BS][1024] bf16 for the output GEMM
  int b = bh >> 4, h = bh & 15;
#pragma unroll
  for (int nt = 0; nt < 4; ++nt)
#pragma unroll
    for (int r = 0; r < 4; ++r) {
      int qr = q0lo + w*16 + u*4 + r;
      Ctx[((size_t)b * 2048 + qr) * 1024 + h*64 + nt*16 + cq] = f2bf(ctx_lo[nt][r]);
    }
#pragma unroll
  for (int nt = 0; nt < 4; ++nt)
#pragma unroll
    for (int r = 0; r < 4; ++r) {
      int qr = q0hi + w*16 + u*4 + r;
      Ctx[((size_t)b * 2048 + qr) * 1024 + h*64 + nt*16 + cq] = f2bf(ctx_hi[nt][r]);
    }
}

// ---------------- LayerNorm over 1024 cols ----------------
__global__ __launch_bounds__(256) void ln_kernel(const float* X, const float* g, const float* b, float* out) {
  int row = blockIdx.x, tid = threadIdx.x;
  float4 v = *(const float4*)(X + (size_t)row * 1024 + tid * 4);
  float s  = v.x + v.y + v.z + v.w;
  float q2 = v.x*v.x + v.y*v.y + v.z*v.z + v.w*v.w;
#pragma unroll
  for (int off = 32; off; off >>= 1) { s += __shfl_xor(s, off); q2 += __shfl_xor(q2, off); }
  __shared__ float red[8];
  int w = tid >> 6, lane = tid & 63;
  if (lane == 0) { red[w] = s; red[4 + w] = q2; }
  __syncthreads();
  s  = red[0] + red[1] + red[2] + red[3];
  q2 = red[4] + red[5] + red[6] + red[7];
  float mean = s * (1.f / 1024.f);
  float var  = q2 * (1.f / 1024.f) - mean * mean;
  float rs   = rsqrtf(var + 1e-5f);
  float4 gv = *(const float4*)(g + tid * 4);
  float4 bv = *(const float4*)(b + tid * 4);
  float4 o;
  o.x = (v.x - mean) * rs * gv.x + bv.x;
  o.y = (v.y - mean) * rs * gv.y + bv.y;
  o.z = (v.z - mean) * rs * gv.z + bv.z;
  o.w = (v.w - mean) * rs * gv.w + bv.w;
  *(float4*)(out + (size_t)row * 1024 + tid * 4) = o;
}

extern "C" void kernel_launch(void* const* d_in, const int* in_sizes, int n_in,
                              void* d_out, int out_size, void* d_ws, size_t ws_size,
                              hipStream_t stream) {
  (void)in_sizes; (void)n_in; (void)out_size; (void)ws_size;
  const float* inQ = (const float*)d_in[0];
  const float* inK = (const float*)d_in[1];
  const float* inV = (const float*)d_in[2];
  const float* Wq  = (const float*)d_in[4];
  const float* Wk  = (const float*)d_in[5];
  const float* Wv  = (const float*)d_in[6];
  const float* Wo  = (const float*)d_in[7];
  const float* gam = (const float*)d_in[8];
  const float* bet = (const float*)d_in[9];
  float* out   = (float*)d_out;
  float* attnO = out + (size_t)4194304;

  char* ws = (char*)d_ws;
  u16*   WTo    = (u16*)ws;
  u16*   Qh     = (u16*)(ws + 2097152);
  u16*   Kh     = (u16*)(ws + 2097152 + (size_t)8388608);
  u16*   VhT    = (u16*)(ws + 2097152 + (size_t)2*8388608);
  u16*   Ctx    = (u16*)(ws + 2097152 + (size_t)3*8388608);
  float* OutLin = (float*)(ws + 2097152 + (size_t)4*8388608);

  // prep scratch lives in attnO[0 .. 30MB): bh0 + most of bh1; fully overwritten
  // by attn probs (lower) + gemm_out ZF=2 zeros (upper) afterwards
  u16* Xbq = (u16*)attnO;
  u16* Xbk = Xbq + (size_t)4194304;
  u16* Xbv = Xbk + (size_t)4194304;
  u16* WTq = Xbv + (size_t)4194304;
  u16* WTk = WTq + (size_t)1048576;
  u16* WTv = WTk + (size_t)1048576;

  prep_kernel<<<dim3(4096, 7), 256, 0, stream>>>(inQ, inK, inV, Xbq, Xbk, Xbv,
                                                 Wq, Wk, Wv, Wo, WTq, WTk, WTv, WTo);
  gemm_qkv<<<dim3(32, 8, 3), 256, 0, stream>>>(Xbq, Xbk, Xbv, WTq, WTk, WTv, Qh, Kh, VhT, attnO);
  attn_fused<<<512, 256, 0, stream>>>(Qh, Kh, VhT, attnO, Ctx);
  gemm_out<<<dim3(32, 8), 256, 0, stream>>>(Ctx, WTo, inQ, OutLin, attnO);
  ln_kernel<<<4096, 256, 0, stream>>>(OutLin, gam, bet, out);
}